// Round 14
// baseline (318.257 us; speedup 1.0000x reference)
//
#include <hip/hip_runtime.h>

typedef __attribute__((ext_vector_type(8))) short bf16x8;
typedef __attribute__((ext_vector_type(4))) float f32x4;
typedef unsigned short u16;
typedef unsigned int u32;

#define NTOK 144
#define CDIM 192
#define NH 6
#define CH 32
#define C3 576
#define NWIN 64
#define WLON 15
#define SCALE 0.17677669529663687f
#define LOG2E 1.4426950408889634f

// per-head w1 panels, pre-padded to the LDS image: [6][96 rows][200 u16] + tail pad to 1KB mult
#define PAN_U16 19456          // 96*200 = 19200 data + 256 junk pad
#define PANB 38912u            // bytes (38 x 1KB gll chunks)

// ws layout (bytes)
#define OFF_W1H  0u            // 6*38912 = 233472
#define OFF_W2T  233472u       // 192*192*2 = 73728
#define OFF_COMB 307200u       // bf16 frag layout: 384*5184*4*2 = 15925248

__device__ __forceinline__ u16 f2b(float f){
  u32 u = __float_as_uint(f);
  u32 r = u + 0x7FFFu + ((u >> 16) & 1u);   // RNE
  return (u16)(r >> 16);
}
__device__ __forceinline__ u32 pk2(float a, float b){
  return (u32)f2b(a) | ((u32)f2b(b) << 16);
}
__device__ __forceinline__ void gload_lds16(const void* g, void* l){
  __builtin_amdgcn_global_load_lds(
      (const __attribute__((address_space(1))) unsigned int*)g,
      (__attribute__((address_space(3))) unsigned int*)l, 16, 0, 0);
}

// ---------------- prep: w1 -> per-head padded bf16 panels; w2 -> transposed bf16
// panel h rows: 0..31 = q cols h*32.., 32..63 = k cols 192+h*32.., 64..95 = v cols 384+h*32..
extern "C" __global__ __launch_bounds__(256) void prep_weights(
    const float* __restrict__ w1, const float* __restrict__ w2,
    u16* __restrict__ w1hp, u16* __restrict__ w2t){
  int idx = blockIdx.x * 256 + threadIdx.x;
  if (idx < NH * 96 * CDIM){
    int h = idx / (96 * CDIM);
    int rem = idx - h * (96 * CDIM);
    int r = rem / CDIM, k = rem - r * CDIM;
    int which = r >> 5, sub = r & 31;
    int col = which * CDIM + h * 32 + sub;
    w1hp[(size_t)h * PAN_U16 + r * 200 + k] = f2b(w1[(size_t)k * C3 + col]);
  }
  if (idx < CDIM * CDIM){ int k = idx / CDIM; int c = idx - k * CDIM; w2t[c * CDIM + k] = f2b(w2[idx]); }
}

// ---------------- prep: comb (bias+mask)*LOG2E as bf16 in MFMA C-fragment layout.
extern "C" __global__ __launch_bounds__(192) void prep_comb(
    const float* __restrict__ bt, const float* __restrict__ mask,
    const int* __restrict__ pidx, u16* __restrict__ comb){
  int nwh = blockIdx.x;                 // 0..383 = nw*6+h
  int nw = nwh / NH, h = nwh - nw * NH;
  int tl = blockIdx.y * 192 + threadIdx.x;   // 0..5183 = (ti*9+nt)*64+lane
  int ti = tl / 576;
  int rem = tl - ti * 576;
  int nt = rem >> 6, lane = rem & 63;
  int ib = ti * 16 + ((lane >> 4) << 2);
  int j  = nt * 16 + (lane & 15);
  const float* mrow = mask + (size_t)(nw * WLON) * (NTOK * NTOK);
  float v[4];
  #pragma unroll
  for (int r = 0; r < 4; ++r){
    int e = (ib + r) * NTOK + j;
    int pi = pidx[e];
    v[r] = (bt[((size_t)pi * NWIN + nw) * NH + h] + mrow[e]) * LOG2E;
  }
  uint2 out; out.x = pk2(v[0], v[1]); out.y = pk2(v[2], v[3]);
  *reinterpret_cast<uint2*>(comb + ((size_t)nwh * 5184 + tl) * 4) = out;
}

// ---------------- K1: fused qkv+attention, one block per window (192 thr, 3 waves).
// Per head: B-panel via gll (issued during prior head's attn), qkv MFMA from A-regs,
// epilogue -> Q/K/V^T LDS, barrier, attn (R11 path: bf16-comb C-init + prefetch,
// no max-subtract, packed u32 stash). 2 barriers per head. Q/K/V never touch HBM.
extern "C" __global__ __launch_bounds__(192) void fused_qkv_attn(
    const float* __restrict__ x, const u16* __restrict__ w1hp, const float* __restrict__ b1,
    const u16* __restrict__ comb, float* __restrict__ outbuf){
  __shared__ u16 Bl[PAN_U16];      // 38912 B
  __shared__ u16 Ql[NTOK * 40];    // 11520 B
  __shared__ u16 Kl[NTOK * 40];    // 11520 B
  __shared__ u16 Vt[CH * 168];     // 10752 B (tok cols 144..159 zeroed)
  __shared__ u16 Pl[3][16 * 40];   //  3840 B  -> total 76544 B -> 2 blocks/CU
  const int tid = threadIdx.x;
  const int b = blockIdx.x;
  const int nw = b / WLON;
  const int wv = tid >> 6, lane = tid & 63, l15 = lane & 15, l4 = lane >> 4;
  u32* stash32 = reinterpret_cast<u32*>(outbuf);
  const f32x4 zz = {0.f, 0.f, 0.f, 0.f};

  // A fragments: rows wv*48 + mi*16 + l15 of this window, fp32 -> bf16 once (72 VGPR)
  bf16x8 af[3][6];
  const float* xw = x + ((size_t)b * NTOK + wv * 48 + l15) * CDIM + l4 * 8;
  #pragma unroll
  for (int mi = 0; mi < 3; ++mi){
    #pragma unroll
    for (int kk = 0; kk < 6; ++kk){
      float4 f0 = *reinterpret_cast<const float4*>(xw + mi * 16 * CDIM + kk * 32);
      float4 f1 = *reinterpret_cast<const float4*>(xw + mi * 16 * CDIM + kk * 32 + 4);
      union { bf16x8 v; uint4 u; } cv;
      cv.u.x = pk2(f0.x, f0.y); cv.u.y = pk2(f0.z, f0.w);
      cv.u.z = pk2(f1.x, f1.y); cv.u.w = pk2(f1.z, f1.w);
      af[mi][kk] = cv.v;
    }
  }
  // zero V^T token-pad cols 144..159 (once; PV tail reads exact zeros)
  for (int e = tid; e < 256; e += 192){
    int ch = e >> 3, q = e & 7;
    *reinterpret_cast<u32*>(Vt + ch * 168 + NTOK + q * 2) = 0u;
  }
  // stage head-0 B panel
  {
    const char* s0 = (const char*)w1hp + lane * 16;
    char* d0 = (char*)Bl;
    for (int j = wv; j < 38; j += 3) gload_lds16(s0 + j * 1024, d0 + j * 1024);
  }

  #pragma unroll 1
  for (int h = 0; h < NH; ++h){
    __syncthreads();   // BAR0: Bl(h) drained+visible; attn(h-1) fully done (QKV-lds free)

    // ---- qkv for head h: acc[sec][mi][nf], sec 0=q 1=k 2=v
    f32x4 acc[3][3][2];
    #pragma unroll
    for (int s_ = 0; s_ < 3; ++s_)
      #pragma unroll
      for (int mi = 0; mi < 3; ++mi){ acc[s_][mi][0] = zz; acc[s_][mi][1] = zz; }
    #pragma unroll
    for (int kk = 0; kk < 6; ++kk){
      bf16x8 bf_[3][2];
      #pragma unroll
      for (int s_ = 0; s_ < 3; ++s_)
        #pragma unroll
        for (int nf = 0; nf < 2; ++nf)
          bf_[s_][nf] = *reinterpret_cast<const bf16x8*>(
              Bl + (s_ * 32 + nf * 16 + l15) * 200 + kk * 32 + l4 * 8);
      #pragma unroll
      for (int s_ = 0; s_ < 3; ++s_)
        #pragma unroll
        for (int mi = 0; mi < 3; ++mi)
          #pragma unroll
          for (int nf = 0; nf < 2; ++nf)
            acc[s_][mi][nf] = __builtin_amdgcn_mfma_f32_16x16x32_bf16(af[mi][kk], bf_[s_][nf], acc[s_][mi][nf], 0, 0, 0);
    }
    // ---- epilogue: acc -> Q/K/V^T LDS (+bias; Q pre-scaled)
    float bb[3][2];
    #pragma unroll
    for (int s_ = 0; s_ < 3; ++s_)
      #pragma unroll
      for (int nf = 0; nf < 2; ++nf)
        bb[s_][nf] = b1[s_ * CDIM + h * 32 + nf * 16 + l15];
    #pragma unroll
    for (int mi = 0; mi < 3; ++mi){
      int gt0 = wv * 48 + mi * 16 + l4 * 4;
      #pragma unroll
      for (int nf = 0; nf < 2; ++nf){
        int chh = nf * 16 + l15;
        #pragma unroll
        for (int r = 0; r < 4; ++r){
          Ql[(gt0 + r) * 40 + chh] = f2b((acc[0][mi][nf][r] + bb[0][nf]) * (SCALE * LOG2E));
          Kl[(gt0 + r) * 40 + chh] = f2b(acc[1][mi][nf][r] + bb[1][nf]);
        }
        u32 v01 = pk2(acc[2][mi][nf][0] + bb[2][nf], acc[2][mi][nf][1] + bb[2][nf]);
        u32 v23 = pk2(acc[2][mi][nf][2] + bb[2][nf], acc[2][mi][nf][3] + bb[2][nf]);
        *reinterpret_cast<u32*>(Vt + chh * 168 + gt0)     = v01;
        *reinterpret_cast<u32*>(Vt + chh * 168 + gt0 + 2) = v23;
      }
    }
    __syncthreads();   // BAR1: QKV-lds(h) visible; all waves done reading Bl(h)

    // stage next head's B panel — drains at next BAR0, hidden under attn(h)
    if (h < NH - 1){
      const char* sn = (const char*)w1hp + (size_t)(h + 1) * PANB + lane * 16;
      char* dn = (char*)Bl;
      for (int j = wv; j < 38; j += 3) gload_lds16(sn + j * 1024, dn + j * 1024);
    }

    // ---- attn for head h: 3 ti per wave (R11 path from LDS)
    const u16* cb = comb + ((size_t)(nw * NH + h)) * (5184 * 4);
    u16* Pw = Pl[wv];
    uint2 cc[9];
    #pragma unroll
    for (int nt = 0; nt < 9; ++nt)
      cc[nt] = *reinterpret_cast<const uint2*>(cb + ((size_t)((wv * 3) * 9 + nt) * 64 + lane) * 4);
    #pragma unroll 1
    for (int mi = 0; mi < 3; ++mi){
      const int ti = wv * 3 + mi;
      const int tin = (mi < 2) ? ti + 1 : ti;
      uint2 ccn[9];
      #pragma unroll
      for (int nt = 0; nt < 9; ++nt)
        ccn[nt] = *reinterpret_cast<const uint2*>(cb + ((size_t)(tin * 9 + nt) * 64 + lane) * 4);

      bf16x8 aq = *reinterpret_cast<const bf16x8*>(Ql + (ti * 16 + l15) * 40 + l4 * 8);
      f32x4 s[9];
      #pragma unroll
      for (int nt = 0; nt < 9; ++nt){
        f32x4 cf;
        cf[0] = __uint_as_float(cc[nt].x << 16);
        cf[1] = __uint_as_float(cc[nt].x & 0xFFFF0000u);
        cf[2] = __uint_as_float(cc[nt].y << 16);
        cf[3] = __uint_as_float(cc[nt].y & 0xFFFF0000u);
        bf16x8 bk = *reinterpret_cast<const bf16x8*>(Kl + (nt * 16 + l15) * 40 + l4 * 8);
        s[nt] = __builtin_amdgcn_mfma_f32_16x16x32_bf16(aq, bk, cf, 0, 0, 0);
      }
      float invs[4];
      #pragma unroll
      for (int r = 0; r < 4; ++r){
        float sum = 0.f;
        #pragma unroll
        for (int nt = 0; nt < 9; ++nt){
          float p = exp2f(s[nt][r]);
          s[nt][r] = p; sum += p;
        }
        #pragma unroll
        for (int off = 8; off; off >>= 1) sum += __shfl_xor(sum, off, 16);
        invs[r] = 1.0f / sum;
      }
      f32x4 oe = zz, oo = zz;
      #pragma unroll
      for (int kk = 0; kk < 5; ++kk){
        #pragma unroll
        for (int r = 0; r < 4; ++r){
          Pw[(l4 * 4 + r) * 40 + l15] = f2b(s[2 * kk][r]);
          if (kk < 4) Pw[(l4 * 4 + r) * 40 + 16 + l15] = f2b(s[2 * kk + 1][r]);
        }
        int j0 = kk * 32 + l4 * 8;
        bf16x8 ap  = *reinterpret_cast<const bf16x8*>(Pw + l15 * 40 + l4 * 8);
        bf16x8 bve = *reinterpret_cast<const bf16x8*>(Vt + (2 * l15) * 168 + j0);
        bf16x8 bvo = *reinterpret_cast<const bf16x8*>(Vt + (2 * l15 + 1) * 168 + j0);
        if (j0 >= NTOK) ap = bf16x8{0, 0, 0, 0, 0, 0, 0, 0};   // tail: zero P side
        oe = __builtin_amdgcn_mfma_f32_16x16x32_bf16(ap, bve, oe, 0, 0, 0);
        oo = __builtin_amdgcn_mfma_f32_16x16x32_bf16(ap, bvo, oo, 0, 0, 0);
      }
      #pragma unroll
      for (int r = 0; r < 4; ++r){
        size_t t = (size_t)b * NTOK + ti * 16 + l4 * 4 + r;
        float is = invs[r];
        stash32[t * 192 + 96 + h * 16 + l15] = pk2(oe[r] * is, oo[r] * is);
      }
      #pragma unroll
      for (int nt = 0; nt < 9; ++nt) cc[nt] = ccn[nt];
    }
  }
}

// ---------------- K2: out = attn_out @ w2 + b2 — B register-stationary, one-deep A prefetch.
extern "C" __global__ __launch_bounds__(256, 2) void proj_gemm(
    const u16* __restrict__ w2t, const float* __restrict__ b2, float* __restrict__ outbuf){
  const int tid = threadIdx.x;
  const int wid = tid >> 6, lane = tid & 63, l15 = lane & 15, l4 = lane >> 4;
  const int hb = blockIdx.y;             // col half: cols hb*96 .. +96
  const f32x4 zz = {0.f, 0.f, 0.f, 0.f};

  bf16x8 bfr[6][6];
  #pragma unroll
  for (int nf = 0; nf < 6; ++nf)
    #pragma unroll
    for (int kk = 0; kk < 6; ++kk)
      bfr[nf][kk] = *reinterpret_cast<const bf16x8*>(
          w2t + (size_t)(hb * 96 + nf * 16 + l15) * CDIM + kk * 32 + l4 * 8);

  const u16* stash = reinterpret_cast<const u16*>(outbuf);
  const size_t rbase = (size_t)blockIdx.x * 256 + wid * 64;

#define LOADA(dst, mt) { \
    const u16* src_ = stash + (rbase + (mt) * 16 + l15) * 384 + 192 + l4 * 8; \
    _Pragma("unroll") \
    for (int kk = 0; kk < 6; ++kk) dst[kk] = *reinterpret_cast<const bf16x8*>(src_ + kk * 32); }

#define COMPUTE(a_, mt) { \
    f32x4 acc[6]; \
    _Pragma("unroll") \
    for (int nf = 0; nf < 6; ++nf) acc[nf] = zz; \
    _Pragma("unroll") \
    for (int kk = 0; kk < 6; ++kk) \
      _Pragma("unroll") \
      for (int nf = 0; nf < 6; ++nf) \
        acc[nf] = __builtin_amdgcn_mfma_f32_16x16x32_bf16(a_[kk], bfr[nf][kk], acc[nf], 0, 0, 0); \
    _Pragma("unroll") \
    for (int nf = 0; nf < 6; ++nf){ \
      int c = hb * 96 + nf * 16 + l15; \
      float bias = b2[c]; \
      _Pragma("unroll") \
      for (int r = 0; r < 4; ++r) \
        outbuf[(rbase + (mt) * 16 + l4 * 4 + r) * CDIM + c] = acc[nf][r] + bias; } }

  bf16x8 a0[6], a1[6];
  LOADA(a0, 0)
  LOADA(a1, 1) COMPUTE(a0, 0)
  LOADA(a0, 2) COMPUTE(a1, 1)
  LOADA(a1, 3) COMPUTE(a0, 2)
  COMPUTE(a1, 3)
#undef LOADA
#undef COMPUTE
}

extern "C" void kernel_launch(void* const* d_in, const int* in_sizes, int n_in,
                              void* d_out, int out_size, void* d_ws, size_t ws_size,
                              hipStream_t stream){
  const float* x    = (const float*)d_in[0];
  const float* w1   = (const float*)d_in[1];
  const float* b1   = (const float*)d_in[2];
  const float* w2   = (const float*)d_in[3];
  const float* b2   = (const float*)d_in[4];
  const float* bt   = (const float*)d_in[5];
  const float* mask = (const float*)d_in[6];
  const int*   pidx = (const int*)d_in[7];
  (void)in_sizes; (void)n_in; (void)out_size; (void)ws_size;

  char* ws = (char*)d_ws;
  u16*   w1hp = (u16*)(ws + OFF_W1H);
  u16*   w2t  = (u16*)(ws + OFF_W2T);
  u16*   comb = (u16*)(ws + OFF_COMB);
  float* out = (float*)d_out;

  prep_weights<<<dim3(432), dim3(256), 0, stream>>>(w1, w2, w1hp, w2t);
  prep_comb<<<dim3(384, 27), dim3(192), 0, stream>>>(bt, mask, pidx, comb);
  fused_qkv_attn<<<dim3(960), dim3(192), 0, stream>>>(x, w1hp, b1, comb, out);
  proj_gemm<<<dim3(540, 2), dim3(256), 0, stream>>>(w2t, b2, out);
}

// Round 15
// 286.260 us; speedup vs baseline: 1.1118x; 1.1118x over previous
//
#include <hip/hip_runtime.h>

typedef __attribute__((ext_vector_type(8))) short bf16x8;
typedef __attribute__((ext_vector_type(4))) float f32x4;
typedef unsigned short u16;
typedef unsigned int u32;

#define NTOK 144
#define CDIM 192
#define NH 6
#define CH 32
#define C3 576
#define NWIN 64
#define WLON 15
#define SCALE 0.17677669529663687f
#define LOG2E 1.4426950408889634f

// w1t panels stored pre-padded to the LDS image: 9 panels x [64 rows][200 u16] (pad zeroed)
#define BPAD 200
#define PANEL_BYTES 25600u     // 64*200*2

// ws layout (bytes)
#define OFF_W1T  0u            // 9*25600 = 230400
#define OFF_W2T  230400u       // 192*192*2 = 73728
#define OFF_COMB 304128u       // bf16 frag layout: 384*5184*4*2 = 15925248
#define OFF_Q    16229376u     // 960*6*144*32*2 = 53084160
#define OFF_K    69313536u
#define OFF_V    122397696u    // stored transposed: [b][h][ch][144]

__device__ __forceinline__ u16 f2b(float f){
  u32 u = __float_as_uint(f);
  u32 r = u + 0x7FFFu + ((u >> 16) & 1u);   // RNE
  return (u16)(r >> 16);
}
__device__ __forceinline__ u32 pk2(float a, float b){
  return (u32)f2b(a) | ((u32)f2b(b) << 16);
}
__device__ __forceinline__ void gload_lds16(const void* g, void* l){
  __builtin_amdgcn_global_load_lds(
      (const __attribute__((address_space(1))) unsigned int*)g,
      (__attribute__((address_space(3))) unsigned int*)l, 16, 0, 0);
}

// ---------------- prep: w1 -> padded bf16 panels (LDS image); w2 -> plain transposed bf16
extern "C" __global__ __launch_bounds__(256) void prep_weights(
    const float* __restrict__ w1, const float* __restrict__ w2,
    u16* __restrict__ w1tp, u16* __restrict__ w2t){
  int idx = blockIdx.x * 256 + threadIdx.x;
  if (idx < CDIM * C3){
    int k = idx / C3;  int c = idx - k * C3;
    w1tp[(size_t)c * BPAD + k] = f2b(w1[idx]);       // panel nt = rows c in [nt*64,(nt+1)*64)
  }
  if (idx < C3 * 8){                                  // zero row pads (cols 192..199)
    int c = idx >> 3, p = idx & 7;
    w1tp[(size_t)c * BPAD + CDIM + p] = 0;
  }
  if (idx < CDIM * CDIM){ int k = idx / CDIM; int c = idx - k * CDIM; w2t[c * CDIM + k] = f2b(w2[idx]); }
}

// ---------------- prep: comb (bias+mask)*LOG2E as bf16 in MFMA C-fragment layout.
extern "C" __global__ __launch_bounds__(192) void prep_comb(
    const float* __restrict__ bt, const float* __restrict__ mask,
    const int* __restrict__ pidx, u16* __restrict__ comb){
  int nwh = blockIdx.x;                 // 0..383 = nw*6+h
  int nw = nwh / NH, h = nwh - nw * NH;
  int tl = blockIdx.y * 192 + threadIdx.x;   // 0..5183 = (ti*9+nt)*64+lane
  int ti = tl / 576;
  int rem = tl - ti * 576;
  int nt = rem >> 6, lane = rem & 63;
  int ib = ti * 16 + ((lane >> 4) << 2);
  int j  = nt * 16 + (lane & 15);
  const float* mrow = mask + (size_t)(nw * WLON) * (NTOK * NTOK);
  float v[4];
  #pragma unroll
  for (int r = 0; r < 4; ++r){
    int e = (ib + r) * NTOK + j;
    int pi = pidx[e];
    v[r] = (bt[((size_t)pi * NWIN + nw) * NH + h] + mrow[e]) * LOG2E;
  }
  uint2 out; out.x = pk2(v[0], v[1]); out.y = pk2(v[2], v[3]);
  *reinterpret_cast<uint2*>(comb + ((size_t)nwh * 5184 + tl) * 4) = out;
}

// ---------------- K1: qkv v4 (R13, proven) — A register-resident; B via global_load_lds
// into a double-buffered linear LDS image (padding baked into the source). One barrier/nt.
extern "C" __global__ __launch_bounds__(256, 3) void qkv_gemm(
    const float* __restrict__ x, const u16* __restrict__ w1tp, const float* __restrict__ b1,
    u16* __restrict__ qw, u16* __restrict__ kw, u16* __restrict__ vw){
  __shared__ u16 Bl[2][64 * BPAD];   // 2 x 25.6 KB
  const int tid = threadIdx.x;
  const int wid = tid >> 6, lane = tid & 63, l15 = lane & 15, l4 = lane >> 4;
  const size_t row0 = (size_t)blockIdx.x * 128 + wid * 32;
  const f32x4 zz = {0.f, 0.f, 0.f, 0.f};

  bf16x8 af[2][6];
  #pragma unroll
  for (int mf = 0; mf < 2; ++mf){
    const float* src = x + (row0 + mf * 16 + l15) * CDIM + l4 * 8;
    #pragma unroll
    for (int kk = 0; kk < 6; ++kk){
      float4 f0 = *reinterpret_cast<const float4*>(src + kk * 32);
      float4 f1 = *reinterpret_cast<const float4*>(src + kk * 32 + 4);
      union { bf16x8 v; uint4 u; } cv;
      cv.u.x = pk2(f0.x, f0.y); cv.u.y = pk2(f0.z, f0.w);
      cv.u.z = pk2(f1.x, f1.y); cv.u.w = pk2(f1.z, f1.w);
      af[mf][kk] = cv.v;
    }
  }
  int bw_[2], n0_[2];
  #pragma unroll
  for (int mf = 0; mf < 2; ++mf){
    int t0 = (int)row0 + mf * 16 + l4 * 4;
    bw_[mf] = t0 / NTOK; n0_[mf] = t0 - bw_[mf] * NTOK;
  }

  {
    const char* src = (const char*)w1tp + lane * 16;
    char* dst = (char*)&Bl[0][0];
    for (int j = wid; j < 25; j += 4)
      gload_lds16(src + j * 1024, dst + j * 1024);
  }

  int cur = 0;
  #pragma unroll 1
  for (int nt = 0; nt < 9; ++nt){
    __syncthreads();   // vmcnt(0) drain -> Bl[cur] ready; Bl[cur^1] free
    if (nt < 8){
      const char* src = (const char*)w1tp + (size_t)(nt + 1) * PANEL_BYTES + lane * 16;
      char* dst = (char*)&Bl[cur ^ 1][0];
      for (int j = wid; j < 25; j += 4)
        gload_lds16(src + j * 1024, dst + j * 1024);
    }
    f32x4 acc[2][4];
    #pragma unroll
    for (int mf = 0; mf < 2; ++mf)
      #pragma unroll
      for (int nf = 0; nf < 4; ++nf) acc[mf][nf] = zz;
    #pragma unroll
    for (int kk = 0; kk < 6; ++kk){
      bf16x8 bfr[4];
      #pragma unroll
      for (int nf = 0; nf < 4; ++nf)
        bfr[nf] = *reinterpret_cast<const bf16x8*>(&Bl[cur][(nf * 16 + l15) * BPAD + kk * 32 + l4 * 8]);
      #pragma unroll
      for (int mf = 0; mf < 2; ++mf)
        #pragma unroll
        for (int nf = 0; nf < 4; ++nf)
          acc[mf][nf] = __builtin_amdgcn_mfma_f32_16x16x32_bf16(af[mf][kk], bfr[nf], acc[mf][nf], 0, 0, 0);
    }
    int which = nt / 3;
    #pragma unroll
    for (int nf = 0; nf < 4; ++nf){
      int c = nt * 64 + nf * 16 + l15;
      int rem = c - which * CDIM;
      int hh = rem >> 5, chh = rem & 31;
      float bias = b1[c];
      if (which == 2){   // V transposed: one uint2 store per quad
        #pragma unroll
        for (int mf = 0; mf < 2; ++mf){
          uint2 pv;
          pv.x = pk2(acc[mf][nf][0] + bias, acc[mf][nf][1] + bias);
          pv.y = pk2(acc[mf][nf][2] + bias, acc[mf][nf][3] + bias);
          *reinterpret_cast<uint2*>(vw + (((size_t)bw_[mf] * NH + hh) * CH + chh) * NTOK + n0_[mf]) = pv;
        }
      } else {
        u16* base = (which == 0) ? qw : kw;
        float mult = (which == 0) ? (SCALE * LOG2E) : 1.0f;
        #pragma unroll
        for (int mf = 0; mf < 2; ++mf)
          #pragma unroll
          for (int r = 0; r < 4; ++r)
            base[(((size_t)bw_[mf] * NH + hh) * NTOK + n0_[mf] + r) * CH + chh] = f2b((acc[mf][nf][r] + bias) * mult);
      }
    }
    cur ^= 1;
  }
}

// ---------------- K2: attention v8 — comb-slice-aligned blocks.
// 320-thr blocks (5 waves); 3 blocks per comb slice (nw,h): all 5 waves read the SAME
// 41.5 KB comb slice (L1 reuse), XCD swizzle puts a slice's 3 blocks on one XCD (L2
// fetches the slice once). Wave body = R11's proven path (bf16 comb C-init + prefetch,
// no max-subtract, even/odd V pairing + packed u32 stash).
extern "C" __global__ __launch_bounds__(320) void attn_kernel(
    const u16* __restrict__ qw, const u16* __restrict__ kw, const u16* __restrict__ vw,
    const u16* __restrict__ comb, float* __restrict__ outbuf){
  __shared__ u16 Pl[5][16][40];   // per-wave P chunk, pad 40 (6400 B)
  const int tid = threadIdx.x;
  const int wv = tid >> 6, lane = tid & 63, l15 = lane & 15, l4 = lane >> 4;
  // bijective XCD swizzle on 1152 = 8*144: consecutive logical ids share an XCD class
  const int lid = (blockIdx.x & 7) * 144 + (blockIdx.x >> 3);
  const int slice = lid / 3, blk3 = lid - slice * 3;    // slice = nw*6+h
  const int nw = slice / NH, h = slice - nw * NH;
  const int ww = blk3 * 5 + wv;
  const int b = nw * WLON + ww;
  const size_t qkbase = ((size_t)b * NH + h) * (NTOK * CH);
  const size_t vbase  = ((size_t)b * NH + h) * (CH * NTOK);
  const u16* cb = comb + ((size_t)slice) * (5184 * 4);
  u16* Pw = &Pl[wv][0][0];
  u32* stash32 = reinterpret_cast<u32*>(outbuf);
  const f32x4 zz = {0.f, 0.f, 0.f, 0.f};

  // prologue: comb fragments for ti=0 (bf16, 2 dwords per tile)
  uint2 cc[9];
  #pragma unroll
  for (int nt = 0; nt < 9; ++nt)
    cc[nt] = *reinterpret_cast<const uint2*>(cb + ((size_t)nt * 64 + lane) * 4);

  #pragma unroll 1
  for (int ti = 0; ti < 9; ++ti){
    const int tin = (ti < 8) ? ti + 1 : ti;
    uint2 ccn[9];
    #pragma unroll
    for (int nt = 0; nt < 9; ++nt)
      ccn[nt] = *reinterpret_cast<const uint2*>(cb + ((size_t)(tin * 9 + nt) * 64 + lane) * 4);

    bf16x8 aq = *reinterpret_cast<const bf16x8*>(qw + qkbase + (ti * 16 + l15) * CH + l4 * 8);
    f32x4 s[9];
    #pragma unroll
    for (int nt = 0; nt < 9; ++nt){
      f32x4 cf;
      cf[0] = __uint_as_float(cc[nt].x << 16);
      cf[1] = __uint_as_float(cc[nt].x & 0xFFFF0000u);
      cf[2] = __uint_as_float(cc[nt].y << 16);
      cf[3] = __uint_as_float(cc[nt].y & 0xFFFF0000u);
      bf16x8 bk = *reinterpret_cast<const bf16x8*>(kw + qkbase + (nt * 16 + l15) * CH + l4 * 8);
      s[nt] = __builtin_amdgcn_mfma_f32_16x16x32_bf16(aq, bk, cf, 0, 0, 0);
    }
    float invs[4];
    #pragma unroll
    for (int r = 0; r < 4; ++r){
      float sum = 0.f;
      #pragma unroll
      for (int nt = 0; nt < 9; ++nt){
        float p = exp2f(s[nt][r]);
        s[nt][r] = p; sum += p;
      }
      #pragma unroll
      for (int off = 8; off; off >>= 1) sum += __shfl_xor(sum, off, 16);
      invs[r] = 1.0f / sum;   // applied at stash
    }
    f32x4 oe = zz, oo = zz;
    #pragma unroll
    for (int kk = 0; kk < 5; ++kk){
      #pragma unroll
      for (int r = 0; r < 4; ++r){
        Pw[(l4 * 4 + r) * 40 + l15] = f2b(s[2 * kk][r]);
        if (kk < 4) Pw[(l4 * 4 + r) * 40 + 16 + l15] = f2b(s[2 * kk + 1][r]);
      }
      int j0 = kk * 32 + l4 * 8;
      int jc = (j0 < NTOK) ? j0 : 0;          // clamp tail address (stay in-bounds)
      bf16x8 ap = *reinterpret_cast<const bf16x8*>(Pw + l15 * 40 + l4 * 8);
      bf16x8 bve = *reinterpret_cast<const bf16x8*>(vw + vbase + (size_t)(2 * l15) * NTOK + jc);
      bf16x8 bvo = *reinterpret_cast<const bf16x8*>(vw + vbase + (size_t)(2 * l15 + 1) * NTOK + jc);
      if (j0 >= NTOK) ap = bf16x8{0, 0, 0, 0, 0, 0, 0, 0};   // tail K=16: zero P side
      oe = __builtin_amdgcn_mfma_f32_16x16x32_bf16(ap, bve, oe, 0, 0, 0);
      oo = __builtin_amdgcn_mfma_f32_16x16x32_bf16(ap, bvo, oo, 0, 0, 0);
    }
    #pragma unroll
    for (int r = 0; r < 4; ++r){
      size_t t = (size_t)b * NTOK + ti * 16 + l4 * 4 + r;
      float is = invs[r];
      stash32[t * 192 + 96 + h * 16 + l15] = pk2(oe[r] * is, oo[r] * is);
    }
    #pragma unroll
    for (int nt = 0; nt < 9; ++nt) cc[nt] = ccn[nt];
  }
}

// ---------------- K3: out = attn_out @ w2 + b2 — B register-stationary, one-deep A prefetch.
extern "C" __global__ __launch_bounds__(256, 2) void proj_gemm(
    const u16* __restrict__ w2t, const float* __restrict__ b2, float* __restrict__ outbuf){
  const int tid = threadIdx.x;
  const int wid = tid >> 6, lane = tid & 63, l15 = lane & 15, l4 = lane >> 4;
  const int hb = blockIdx.y;             // col half: cols hb*96 .. +96
  const f32x4 zz = {0.f, 0.f, 0.f, 0.f};

  bf16x8 bfr[6][6];
  #pragma unroll
  for (int nf = 0; nf < 6; ++nf)
    #pragma unroll
    for (int kk = 0; kk < 6; ++kk)
      bfr[nf][kk] = *reinterpret_cast<const bf16x8*>(
          w2t + (size_t)(hb * 96 + nf * 16 + l15) * CDIM + kk * 32 + l4 * 8);

  const u16* stash = reinterpret_cast<const u16*>(outbuf);
  const size_t rbase = (size_t)blockIdx.x * 256 + wid * 64;

#define LOADA(dst, mt) { \
    const u16* src_ = stash + (rbase + (mt) * 16 + l15) * 384 + 192 + l4 * 8; \
    _Pragma("unroll") \
    for (int kk = 0; kk < 6; ++kk) dst[kk] = *reinterpret_cast<const bf16x8*>(src_ + kk * 32); }

#define COMPUTE(a_, mt) { \
    f32x4 acc[6]; \
    _Pragma("unroll") \
    for (int nf = 0; nf < 6; ++nf) acc[nf] = zz; \
    _Pragma("unroll") \
    for (int kk = 0; kk < 6; ++kk) \
      _Pragma("unroll") \
      for (int nf = 0; nf < 6; ++nf) \
        acc[nf] = __builtin_amdgcn_mfma_f32_16x16x32_bf16(a_[kk], bfr[nf][kk], acc[nf], 0, 0, 0); \
    _Pragma("unroll") \
    for (int nf = 0; nf < 6; ++nf){ \
      int c = hb * 96 + nf * 16 + l15; \
      float bias = b2[c]; \
      _Pragma("unroll") \
      for (int r = 0; r < 4; ++r) \
        outbuf[(rbase + (mt) * 16 + l4 * 4 + r) * CDIM + c] = acc[nf][r] + bias; } }

  bf16x8 a0[6], a1[6];
  LOADA(a0, 0)
  LOADA(a1, 1) COMPUTE(a0, 0)
  LOADA(a0, 2) COMPUTE(a1, 1)
  LOADA(a1, 3) COMPUTE(a0, 2)
  COMPUTE(a1, 3)
#undef LOADA
#undef COMPUTE
}

extern "C" void kernel_launch(void* const* d_in, const int* in_sizes, int n_in,
                              void* d_out, int out_size, void* d_ws, size_t ws_size,
                              hipStream_t stream){
  const float* x    = (const float*)d_in[0];
  const float* w1   = (const float*)d_in[1];
  const float* b1   = (const float*)d_in[2];
  const float* w2   = (const float*)d_in[3];
  const float* b2   = (const float*)d_in[4];
  const float* bt   = (const float*)d_in[5];
  const float* mask = (const float*)d_in[6];
  const int*   pidx = (const int*)d_in[7];
  (void)in_sizes; (void)n_in; (void)out_size; (void)ws_size;

  char* ws = (char*)d_ws;
  u16*   w1tp = (u16*)(ws + OFF_W1T);
  u16*   w2t  = (u16*)(ws + OFF_W2T);
  u16*   comb = (u16*)(ws + OFF_COMB);
  u16*   qw   = (u16*)(ws + OFF_Q);
  u16*   kw   = (u16*)(ws + OFF_K);
  u16*   vw   = (u16*)(ws + OFF_V);
  float* out = (float*)d_out;

  prep_weights<<<dim3(432), dim3(256), 0, stream>>>(w1, w2, w1tp, w2t);
  prep_comb<<<dim3(384, 27), dim3(192), 0, stream>>>(bt, mask, pidx, comb);
  qkv_gemm<<<dim3(1080), dim3(256), 0, stream>>>(x, w1tp, b1, qw, kw, vw);
  attn_kernel<<<dim3(1152), dim3(320), 0, stream>>>(qw, kw, vw, comb, out);
  proj_gemm<<<dim3(540, 2), dim3(256), 0, stream>>>(w2t, b2, out);
}

// Round 16
// 251.731 us; speedup vs baseline: 1.2643x; 1.1372x over previous
//
#include <hip/hip_runtime.h>

typedef __attribute__((ext_vector_type(8))) short bf16x8;
typedef __attribute__((ext_vector_type(4))) float f32x4;
typedef unsigned short u16;
typedef unsigned int u32;

#define NTOK 144
#define CDIM 192
#define NH 6
#define CH 32
#define C3 576
#define NWIN 64
#define WLON 15
#define SCALE 0.17677669529663687f
#define LOG2E 1.4426950408889634f

// w1t panels stored pre-padded to the LDS image: 9 panels x [64 rows][200 u16] (pad zeroed)
#define BPAD 200
#define PANEL_BYTES 25600u     // 64*200*2

// ws layout (bytes)
#define OFF_W1T  0u            // 9*25600 = 230400
#define OFF_W2T  230400u       // 192*192*2 = 73728
#define OFF_COMB 304128u       // bf16 frag layout: 384*5184*4*2 = 15925248
#define OFF_Q    16229376u     // 960*6*144*32*2 = 53084160
#define OFF_K    69313536u
#define OFF_V    122397696u    // stored transposed: [b][h][ch][144]

__device__ __forceinline__ u16 f2b(float f){
  u32 u = __float_as_uint(f);
  u32 r = u + 0x7FFFu + ((u >> 16) & 1u);   // RNE
  return (u16)(r >> 16);
}
__device__ __forceinline__ u32 pk2(float a, float b){
  return (u32)f2b(a) | ((u32)f2b(b) << 16);
}
__device__ __forceinline__ void gload_lds16(const void* g, void* l){
  __builtin_amdgcn_global_load_lds(
      (const __attribute__((address_space(1))) unsigned int*)g,
      (__attribute__((address_space(3))) unsigned int*)l, 16, 0, 0);
}

// ---------------- prep: w1 -> padded bf16 panels (LDS image); w2 -> plain transposed bf16
extern "C" __global__ __launch_bounds__(256) void prep_weights(
    const float* __restrict__ w1, const float* __restrict__ w2,
    u16* __restrict__ w1tp, u16* __restrict__ w2t){
  int idx = blockIdx.x * 256 + threadIdx.x;
  if (idx < CDIM * C3){
    int k = idx / C3;  int c = idx - k * C3;
    w1tp[(size_t)c * BPAD + k] = f2b(w1[idx]);       // panel nt = rows c in [nt*64,(nt+1)*64)
  }
  if (idx < C3 * 8){                                  // zero row pads (cols 192..199)
    int c = idx >> 3, p = idx & 7;
    w1tp[(size_t)c * BPAD + CDIM + p] = 0;
  }
  if (idx < CDIM * CDIM){ int k = idx / CDIM; int c = idx - k * CDIM; w2t[c * CDIM + k] = f2b(w2[idx]); }
}

// ---------------- prep: comb (bias+mask)*LOG2E as bf16 in MFMA C-fragment layout.
extern "C" __global__ __launch_bounds__(192) void prep_comb(
    const float* __restrict__ bt, const float* __restrict__ mask,
    const int* __restrict__ pidx, u16* __restrict__ comb){
  int nwh = blockIdx.x;                 // 0..383 = nw*6+h
  int nw = nwh / NH, h = nwh - nw * NH;
  int tl = blockIdx.y * 192 + threadIdx.x;   // 0..5183 = (ti*9+nt)*64+lane
  int ti = tl / 576;
  int rem = tl - ti * 576;
  int nt = rem >> 6, lane = rem & 63;
  int ib = ti * 16 + ((lane >> 4) << 2);
  int j  = nt * 16 + (lane & 15);
  const float* mrow = mask + (size_t)(nw * WLON) * (NTOK * NTOK);
  float v[4];
  #pragma unroll
  for (int r = 0; r < 4; ++r){
    int e = (ib + r) * NTOK + j;
    int pi = pidx[e];
    v[r] = (bt[((size_t)pi * NWIN + nw) * NH + h] + mrow[e]) * LOG2E;
  }
  uint2 out; out.x = pk2(v[0], v[1]); out.y = pk2(v[2], v[3]);
  *reinterpret_cast<uint2*>(comb + ((size_t)nwh * 5184 + tl) * 4) = out;
}

// ---------------- K1: qkv v4 (R13, proven) — A register-resident; B via global_load_lds
// into a double-buffered linear LDS image (padding baked into the source). One barrier/nt.
extern "C" __global__ __launch_bounds__(256, 3) void qkv_gemm(
    const float* __restrict__ x, const u16* __restrict__ w1tp, const float* __restrict__ b1,
    u16* __restrict__ qw, u16* __restrict__ kw, u16* __restrict__ vw){
  __shared__ u16 Bl[2][64 * BPAD];   // 2 x 25.6 KB
  const int tid = threadIdx.x;
  const int wid = tid >> 6, lane = tid & 63, l15 = lane & 15, l4 = lane >> 4;
  const size_t row0 = (size_t)blockIdx.x * 128 + wid * 32;
  const f32x4 zz = {0.f, 0.f, 0.f, 0.f};

  bf16x8 af[2][6];
  #pragma unroll
  for (int mf = 0; mf < 2; ++mf){
    const float* src = x + (row0 + mf * 16 + l15) * CDIM + l4 * 8;
    #pragma unroll
    for (int kk = 0; kk < 6; ++kk){
      float4 f0 = *reinterpret_cast<const float4*>(src + kk * 32);
      float4 f1 = *reinterpret_cast<const float4*>(src + kk * 32 + 4);
      union { bf16x8 v; uint4 u; } cv;
      cv.u.x = pk2(f0.x, f0.y); cv.u.y = pk2(f0.z, f0.w);
      cv.u.z = pk2(f1.x, f1.y); cv.u.w = pk2(f1.z, f1.w);
      af[mf][kk] = cv.v;
    }
  }
  int bw_[2], n0_[2];
  #pragma unroll
  for (int mf = 0; mf < 2; ++mf){
    int t0 = (int)row0 + mf * 16 + l4 * 4;
    bw_[mf] = t0 / NTOK; n0_[mf] = t0 - bw_[mf] * NTOK;
  }

  {
    const char* src = (const char*)w1tp + lane * 16;
    char* dst = (char*)&Bl[0][0];
    for (int j = wid; j < 25; j += 4)
      gload_lds16(src + j * 1024, dst + j * 1024);
  }

  int cur = 0;
  #pragma unroll 1
  for (int nt = 0; nt < 9; ++nt){
    __syncthreads();   // vmcnt(0) drain -> Bl[cur] ready; Bl[cur^1] free
    if (nt < 8){
      const char* src = (const char*)w1tp + (size_t)(nt + 1) * PANEL_BYTES + lane * 16;
      char* dst = (char*)&Bl[cur ^ 1][0];
      for (int j = wid; j < 25; j += 4)
        gload_lds16(src + j * 1024, dst + j * 1024);
    }
    f32x4 acc[2][4];
    #pragma unroll
    for (int mf = 0; mf < 2; ++mf)
      #pragma unroll
      for (int nf = 0; nf < 4; ++nf) acc[mf][nf] = zz;
    #pragma unroll
    for (int kk = 0; kk < 6; ++kk){
      bf16x8 bfr[4];
      #pragma unroll
      for (int nf = 0; nf < 4; ++nf)
        bfr[nf] = *reinterpret_cast<const bf16x8*>(&Bl[cur][(nf * 16 + l15) * BPAD + kk * 32 + l4 * 8]);
      #pragma unroll
      for (int mf = 0; mf < 2; ++mf)
        #pragma unroll
        for (int nf = 0; nf < 4; ++nf)
          acc[mf][nf] = __builtin_amdgcn_mfma_f32_16x16x32_bf16(af[mf][kk], bfr[nf], acc[mf][nf], 0, 0, 0);
    }
    int which = nt / 3;
    #pragma unroll
    for (int nf = 0; nf < 4; ++nf){
      int c = nt * 64 + nf * 16 + l15;
      int rem = c - which * CDIM;
      int hh = rem >> 5, chh = rem & 31;
      float bias = b1[c];
      if (which == 2){   // V transposed: one uint2 store per quad
        #pragma unroll
        for (int mf = 0; mf < 2; ++mf){
          uint2 pv;
          pv.x = pk2(acc[mf][nf][0] + bias, acc[mf][nf][1] + bias);
          pv.y = pk2(acc[mf][nf][2] + bias, acc[mf][nf][3] + bias);
          *reinterpret_cast<uint2*>(vw + (((size_t)bw_[mf] * NH + hh) * CH + chh) * NTOK + n0_[mf]) = pv;
        }
      } else {
        u16* base = (which == 0) ? qw : kw;
        float mult = (which == 0) ? (SCALE * LOG2E) : 1.0f;
        #pragma unroll
        for (int mf = 0; mf < 2; ++mf)
          #pragma unroll
          for (int r = 0; r < 4; ++r)
            base[(((size_t)bw_[mf] * NH + hh) * NTOK + n0_[mf] + r) * CH + chh] = f2b((acc[mf][nf][r] + bias) * mult);
      }
    }
    cur ^= 1;
  }
}

// ---------------- K2: fused attention + projection — one block per window (384 thr, 6 waves).
// Wave h = head h: R11's proven attn path (bf16 comb C-init + prefetch, no max-subtract,
// even/odd V pairing) writing O-columns bf16 into LDS Olds[144][200] (k-contiguous).
// One barrier; then wave h computes proj's 32-col slice: 12 register-stationary w2t frags
// (L2-hit, loaded once) x A-frags from Olds (conflict-free ds_read_b128). No stash traffic.
extern "C" __global__ __launch_bounds__(384) void attn_proj(
    const u16* __restrict__ qw, const u16* __restrict__ kw, const u16* __restrict__ vw,
    const u16* __restrict__ comb, const u16* __restrict__ w2t, const float* __restrict__ b2,
    float* __restrict__ outbuf){
  __shared__ u16 Olds[NTOK * 200];   // 57600 B: [t][c], c = 0..191 (k-dim), +8 pad
  __shared__ u16 Pl[6][16][40];      //  7680 B: per-wave P chunk
  const int tid = threadIdx.x;
  const int b = blockIdx.x;
  const int h = tid >> 6;            // wave = head
  const int lane = tid & 63, l15 = lane & 15, l4 = lane >> 4;
  const size_t qkbase = ((size_t)b * NH + h) * (NTOK * CH);
  const size_t vbase  = ((size_t)b * NH + h) * (CH * NTOK);
  const u16* cb = comb + ((size_t)((b / WLON) * NH + h)) * (5184 * 4);
  u16* Pw = &Pl[h][0][0];
  u32* O32 = reinterpret_cast<u32*>(Olds);
  const f32x4 zz = {0.f, 0.f, 0.f, 0.f};

  // ---- attn phase (R11 path, output -> LDS)
  uint2 cc[9];
  #pragma unroll
  for (int nt = 0; nt < 9; ++nt)
    cc[nt] = *reinterpret_cast<const uint2*>(cb + ((size_t)nt * 64 + lane) * 4);

  #pragma unroll 1
  for (int ti = 0; ti < 9; ++ti){
    const int tin = (ti < 8) ? ti + 1 : ti;
    uint2 ccn[9];
    #pragma unroll
    for (int nt = 0; nt < 9; ++nt)
      ccn[nt] = *reinterpret_cast<const uint2*>(cb + ((size_t)(tin * 9 + nt) * 64 + lane) * 4);

    bf16x8 aq = *reinterpret_cast<const bf16x8*>(qw + qkbase + (ti * 16 + l15) * CH + l4 * 8);
    f32x4 s[9];
    #pragma unroll
    for (int nt = 0; nt < 9; ++nt){
      f32x4 cf;
      cf[0] = __uint_as_float(cc[nt].x << 16);
      cf[1] = __uint_as_float(cc[nt].x & 0xFFFF0000u);
      cf[2] = __uint_as_float(cc[nt].y << 16);
      cf[3] = __uint_as_float(cc[nt].y & 0xFFFF0000u);
      bf16x8 bk = *reinterpret_cast<const bf16x8*>(kw + qkbase + (nt * 16 + l15) * CH + l4 * 8);
      s[nt] = __builtin_amdgcn_mfma_f32_16x16x32_bf16(aq, bk, cf, 0, 0, 0);
    }
    float invs[4];
    #pragma unroll
    for (int r = 0; r < 4; ++r){
      float sum = 0.f;
      #pragma unroll
      for (int nt = 0; nt < 9; ++nt){
        float p = exp2f(s[nt][r]);
        s[nt][r] = p; sum += p;
      }
      #pragma unroll
      for (int off = 8; off; off >>= 1) sum += __shfl_xor(sum, off, 16);
      invs[r] = 1.0f / sum;
    }
    f32x4 oe = zz, oo = zz;
    #pragma unroll
    for (int kk = 0; kk < 5; ++kk){
      #pragma unroll
      for (int r = 0; r < 4; ++r){
        Pw[(l4 * 4 + r) * 40 + l15] = f2b(s[2 * kk][r]);
        if (kk < 4) Pw[(l4 * 4 + r) * 40 + 16 + l15] = f2b(s[2 * kk + 1][r]);
      }
      int j0 = kk * 32 + l4 * 8;
      int jc = (j0 < NTOK) ? j0 : 0;          // clamp tail address (stay in-bounds)
      bf16x8 ap = *reinterpret_cast<const bf16x8*>(Pw + l15 * 40 + l4 * 8);
      bf16x8 bve = *reinterpret_cast<const bf16x8*>(vw + vbase + (size_t)(2 * l15) * NTOK + jc);
      bf16x8 bvo = *reinterpret_cast<const bf16x8*>(vw + vbase + (size_t)(2 * l15 + 1) * NTOK + jc);
      if (j0 >= NTOK) ap = bf16x8{0, 0, 0, 0, 0, 0, 0, 0};   // tail K=16: zero P side
      oe = __builtin_amdgcn_mfma_f32_16x16x32_bf16(ap, bve, oe, 0, 0, 0);
      oo = __builtin_amdgcn_mfma_f32_16x16x32_bf16(ap, bvo, oo, 0, 0, 0);
    }
    // O columns (2*l15, 2*l15+1) of head h -> LDS, one u32 per row (u32 stride 100)
    #pragma unroll
    for (int r = 0; r < 4; ++r){
      int t = ti * 16 + l4 * 4 + r;
      float is = invs[r];
      O32[t * 100 + h * 16 + l15] = pk2(oe[r] * is, oo[r] * is);
    }
    #pragma unroll
    for (int nt = 0; nt < 9; ++nt) cc[nt] = ccn[nt];
  }

  // ---- proj phase: wave h -> output cols h*32 .. h*32+31
  // B-frags (w2t rows h*32+nf*16+l15, k-contig): loaded once, L2-resident
  bf16x8 bfr[2][6];
  #pragma unroll
  for (int nf = 0; nf < 2; ++nf)
    #pragma unroll
    for (int kk = 0; kk < 6; ++kk)
      bfr[nf][kk] = *reinterpret_cast<const bf16x8*>(
          w2t + (size_t)(h * 32 + nf * 16 + l15) * CDIM + kk * 32 + l4 * 8);
  float bias[2];
  #pragma unroll
  for (int nf = 0; nf < 2; ++nf) bias[nf] = b2[h * 32 + nf * 16 + l15];

  __syncthreads();   // all heads' O visible

  #pragma unroll 1
  for (int mt = 0; mt < 9; ++mt){
    bf16x8 afr[6];
    #pragma unroll
    for (int kk = 0; kk < 6; ++kk)
      afr[kk] = *reinterpret_cast<const bf16x8*>(Olds + (mt * 16 + l15) * 200 + kk * 32 + l4 * 8);
    f32x4 acc[2];
    acc[0] = zz; acc[1] = zz;
    #pragma unroll
    for (int kk = 0; kk < 6; ++kk){
      acc[0] = __builtin_amdgcn_mfma_f32_16x16x32_bf16(afr[kk], bfr[0][kk], acc[0], 0, 0, 0);
      acc[1] = __builtin_amdgcn_mfma_f32_16x16x32_bf16(afr[kk], bfr[1][kk], acc[1], 0, 0, 0);
    }
    #pragma unroll
    for (int nf = 0; nf < 2; ++nf){
      int c = h * 32 + nf * 16 + l15;
      #pragma unroll
      for (int r = 0; r < 4; ++r)
        outbuf[((size_t)b * NTOK + mt * 16 + l4 * 4 + r) * CDIM + c] = acc[nf][r] + bias[nf];
    }
  }
}

extern "C" void kernel_launch(void* const* d_in, const int* in_sizes, int n_in,
                              void* d_out, int out_size, void* d_ws, size_t ws_size,
                              hipStream_t stream){
  const float* x    = (const float*)d_in[0];
  const float* w1   = (const float*)d_in[1];
  const float* b1   = (const float*)d_in[2];
  const float* w2   = (const float*)d_in[3];
  const float* b2   = (const float*)d_in[4];
  const float* bt   = (const float*)d_in[5];
  const float* mask = (const float*)d_in[6];
  const int*   pidx = (const int*)d_in[7];
  (void)in_sizes; (void)n_in; (void)out_size; (void)ws_size;

  char* ws = (char*)d_ws;
  u16*   w1tp = (u16*)(ws + OFF_W1T);
  u16*   w2t  = (u16*)(ws + OFF_W2T);
  u16*   comb = (u16*)(ws + OFF_COMB);
  u16*   qw   = (u16*)(ws + OFF_Q);
  u16*   kw   = (u16*)(ws + OFF_K);
  u16*   vw   = (u16*)(ws + OFF_V);
  float* out = (float*)d_out;

  prep_weights<<<dim3(432), dim3(256), 0, stream>>>(w1, w2, w1tp, w2t);
  prep_comb<<<dim3(384, 27), dim3(192), 0, stream>>>(bt, mask, pidx, comb);
  qkv_gemm<<<dim3(1080), dim3(256), 0, stream>>>(x, w1tp, b1, qw, kw, vw);
  attn_proj<<<dim3(960), dim3(384), 0, stream>>>(qw, kw, vw, comb, w2t, b2, out);
}

// Round 17
// 250.168 us; speedup vs baseline: 1.2722x; 1.0062x over previous
//
#include <hip/hip_runtime.h>

typedef __attribute__((ext_vector_type(8))) short bf16x8;
typedef __attribute__((ext_vector_type(4))) float f32x4;
typedef unsigned short u16;
typedef unsigned int u32;

#define NTOK 144
#define CDIM 192
#define NH 6
#define CH 32
#define C3 576
#define NWIN 64
#define WLON 15
#define SCALE 0.17677669529663687f
#define LOG2E 1.4426950408889634f

// w1t panels stored pre-padded to the LDS image: 9 panels x [64 rows][200 u16] (pad zeroed)
#define BPAD 200
#define PANEL_BYTES 25600u     // 64*200*2

// ws layout (bytes)
#define OFF_W1T  0u            // 9*25600 = 230400
#define OFF_W2T  230400u       // 192*192*2 = 73728
#define OFF_COMB 304128u       // bf16 frag layout: 384*5184*4*2 = 15925248
#define OFF_Q    16229376u     // 960*6*144*32*2 = 53084160
#define OFF_K    69313536u
#define OFF_V    122397696u    // stored transposed: [b][h][ch][144]

__device__ __forceinline__ u16 f2b(float f){
  u32 u = __float_as_uint(f);
  u32 r = u + 0x7FFFu + ((u >> 16) & 1u);   // RNE
  return (u16)(r >> 16);
}
__device__ __forceinline__ u32 pk2(float a, float b){
  return (u32)f2b(a) | ((u32)f2b(b) << 16);
}
__device__ __forceinline__ void gload_lds16(const void* g, void* l){
  __builtin_amdgcn_global_load_lds(
      (const __attribute__((address_space(1))) unsigned int*)g,
      (__attribute__((address_space(3))) unsigned int*)l, 16, 0, 0);
}

// ---------------- prep: w1 -> padded bf16 panels (LDS image); w2 -> plain transposed bf16
extern "C" __global__ __launch_bounds__(256) void prep_weights(
    const float* __restrict__ w1, const float* __restrict__ w2,
    u16* __restrict__ w1tp, u16* __restrict__ w2t){
  int idx = blockIdx.x * 256 + threadIdx.x;
  if (idx < CDIM * C3){
    int k = idx / C3;  int c = idx - k * C3;
    w1tp[(size_t)c * BPAD + k] = f2b(w1[idx]);       // panel nt = rows c in [nt*64,(nt+1)*64)
  }
  if (idx < C3 * 8){                                  // zero row pads (cols 192..199)
    int c = idx >> 3, p = idx & 7;
    w1tp[(size_t)c * BPAD + CDIM + p] = 0;
  }
  if (idx < CDIM * CDIM){ int k = idx / CDIM; int c = idx - k * CDIM; w2t[c * CDIM + k] = f2b(w2[idx]); }
}

// ---------------- prep: comb (bias+mask)*LOG2E as bf16 in MFMA C-fragment layout.
extern "C" __global__ __launch_bounds__(192) void prep_comb(
    const float* __restrict__ bt, const float* __restrict__ mask,
    const int* __restrict__ pidx, u16* __restrict__ comb){
  int nwh = blockIdx.x;                 // 0..383 = nw*6+h
  int nw = nwh / NH, h = nwh - nw * NH;
  int tl = blockIdx.y * 192 + threadIdx.x;   // 0..5183 = (ti*9+nt)*64+lane
  int ti = tl / 576;
  int rem = tl - ti * 576;
  int nt = rem >> 6, lane = rem & 63;
  int ib = ti * 16 + ((lane >> 4) << 2);
  int j  = nt * 16 + (lane & 15);
  const float* mrow = mask + (size_t)(nw * WLON) * (NTOK * NTOK);
  float v[4];
  #pragma unroll
  for (int r = 0; r < 4; ++r){
    int e = (ib + r) * NTOK + j;
    int pi = pidx[e];
    v[r] = (bt[((size_t)pi * NWIN + nw) * NH + h] + mrow[e]) * LOG2E;
  }
  uint2 out; out.x = pk2(v[0], v[1]); out.y = pk2(v[2], v[3]);
  *reinterpret_cast<uint2*>(comb + ((size_t)nwh * 5184 + tl) * 4) = out;
}

// ---------------- K1: qkv v4 (R13, proven) — A register-resident; B via global_load_lds
// into a double-buffered linear LDS image (padding baked into the source). One barrier/nt.
extern "C" __global__ __launch_bounds__(256, 3) void qkv_gemm(
    const float* __restrict__ x, const u16* __restrict__ w1tp, const float* __restrict__ b1,
    u16* __restrict__ qw, u16* __restrict__ kw, u16* __restrict__ vw){
  __shared__ u16 Bl[2][64 * BPAD];   // 2 x 25.6 KB
  const int tid = threadIdx.x;
  const int wid = tid >> 6, lane = tid & 63, l15 = lane & 15, l4 = lane >> 4;
  const size_t row0 = (size_t)blockIdx.x * 128 + wid * 32;
  const f32x4 zz = {0.f, 0.f, 0.f, 0.f};

  bf16x8 af[2][6];
  #pragma unroll
  for (int mf = 0; mf < 2; ++mf){
    const float* src = x + (row0 + mf * 16 + l15) * CDIM + l4 * 8;
    #pragma unroll
    for (int kk = 0; kk < 6; ++kk){
      float4 f0 = *reinterpret_cast<const float4*>(src + kk * 32);
      float4 f1 = *reinterpret_cast<const float4*>(src + kk * 32 + 4);
      union { bf16x8 v; uint4 u; } cv;
      cv.u.x = pk2(f0.x, f0.y); cv.u.y = pk2(f0.z, f0.w);
      cv.u.z = pk2(f1.x, f1.y); cv.u.w = pk2(f1.z, f1.w);
      af[mf][kk] = cv.v;
    }
  }
  int bw_[2], n0_[2];
  #pragma unroll
  for (int mf = 0; mf < 2; ++mf){
    int t0 = (int)row0 + mf * 16 + l4 * 4;
    bw_[mf] = t0 / NTOK; n0_[mf] = t0 - bw_[mf] * NTOK;
  }

  {
    const char* src = (const char*)w1tp + lane * 16;
    char* dst = (char*)&Bl[0][0];
    for (int j = wid; j < 25; j += 4)
      gload_lds16(src + j * 1024, dst + j * 1024);
  }

  int cur = 0;
  #pragma unroll 1
  for (int nt = 0; nt < 9; ++nt){
    __syncthreads();   // vmcnt(0) drain -> Bl[cur] ready; Bl[cur^1] free
    if (nt < 8){
      const char* src = (const char*)w1tp + (size_t)(nt + 1) * PANEL_BYTES + lane * 16;
      char* dst = (char*)&Bl[cur ^ 1][0];
      for (int j = wid; j < 25; j += 4)
        gload_lds16(src + j * 1024, dst + j * 1024);
    }
    f32x4 acc[2][4];
    #pragma unroll
    for (int mf = 0; mf < 2; ++mf)
      #pragma unroll
      for (int nf = 0; nf < 4; ++nf) acc[mf][nf] = zz;
    #pragma unroll
    for (int kk = 0; kk < 6; ++kk){
      bf16x8 bfr[4];
      #pragma unroll
      for (int nf = 0; nf < 4; ++nf)
        bfr[nf] = *reinterpret_cast<const bf16x8*>(&Bl[cur][(nf * 16 + l15) * BPAD + kk * 32 + l4 * 8]);
      #pragma unroll
      for (int mf = 0; mf < 2; ++mf)
        #pragma unroll
        for (int nf = 0; nf < 4; ++nf)
          acc[mf][nf] = __builtin_amdgcn_mfma_f32_16x16x32_bf16(af[mf][kk], bfr[nf], acc[mf][nf], 0, 0, 0);
    }
    int which = nt / 3;
    #pragma unroll
    for (int nf = 0; nf < 4; ++nf){
      int c = nt * 64 + nf * 16 + l15;
      int rem = c - which * CDIM;
      int hh = rem >> 5, chh = rem & 31;
      float bias = b1[c];
      if (which == 2){   // V transposed: one uint2 store per quad
        #pragma unroll
        for (int mf = 0; mf < 2; ++mf){
          uint2 pv;
          pv.x = pk2(acc[mf][nf][0] + bias, acc[mf][nf][1] + bias);
          pv.y = pk2(acc[mf][nf][2] + bias, acc[mf][nf][3] + bias);
          *reinterpret_cast<uint2*>(vw + (((size_t)bw_[mf] * NH + hh) * CH + chh) * NTOK + n0_[mf]) = pv;
        }
      } else {
        u16* base = (which == 0) ? qw : kw;
        float mult = (which == 0) ? (SCALE * LOG2E) : 1.0f;
        #pragma unroll
        for (int mf = 0; mf < 2; ++mf)
          #pragma unroll
          for (int r = 0; r < 4; ++r)
            base[(((size_t)bw_[mf] * NH + hh) * NTOK + n0_[mf] + r) * CH + chh] = f2b((acc[mf][nf][r] + bias) * mult);
      }
    }
    cur ^= 1;
  }
}

// ---------------- K2: attention v9 — R13's proven 512-thr/8-wave shape; ONLY the
// wave->work mapping changes: slice-major (gw = slice*15+ww), so a block's 8 waves
// span <=2 comb slices (vs 8), and a bijective XCD swizzle (720 = 8*90) keeps each
// slice's 15 waves on one XCD -> comb fetched ~once per slice per L2.
extern "C" __global__ __launch_bounds__(512) void attn_kernel(
    const u16* __restrict__ qw, const u16* __restrict__ kw, const u16* __restrict__ vw,
    const u16* __restrict__ comb, float* __restrict__ outbuf){
  __shared__ u16 Pl[8][16][40];   // per-wave P chunk, pad 40 (10240 B)
  const int tid = threadIdx.x;
  const int wv = tid >> 6, lane = tid & 63, l15 = lane & 15, l4 = lane >> 4;
  const int lid = (blockIdx.x & 7) * 90 + (blockIdx.x >> 3);   // bijective on 720
  const int gw = lid * 8 + wv;              // slice-major: 0..5759 = slice*15 + ww
  const int slice = gw / WLON, ww = gw - slice * WLON;
  const int nw = slice / NH, h = slice - nw * NH;
  const int b = nw * WLON + ww;
  const size_t qkbase = ((size_t)b * NH + h) * (NTOK * CH);
  const size_t vbase  = ((size_t)b * NH + h) * (CH * NTOK);
  const u16* cb = comb + (size_t)slice * (5184 * 4);
  u16* Pw = &Pl[wv][0][0];
  u32* stash32 = reinterpret_cast<u32*>(outbuf);
  const f32x4 zz = {0.f, 0.f, 0.f, 0.f};

  // prologue: comb fragments for ti=0 (bf16, 2 dwords per tile)
  uint2 cc[9];
  #pragma unroll
  for (int nt = 0; nt < 9; ++nt)
    cc[nt] = *reinterpret_cast<const uint2*>(cb + ((size_t)nt * 64 + lane) * 4);

  #pragma unroll 1
  for (int ti = 0; ti < 9; ++ti){
    const int tin = (ti < 8) ? ti + 1 : ti;
    uint2 ccn[9];
    #pragma unroll
    for (int nt = 0; nt < 9; ++nt)
      ccn[nt] = *reinterpret_cast<const uint2*>(cb + ((size_t)(tin * 9 + nt) * 64 + lane) * 4);

    bf16x8 aq = *reinterpret_cast<const bf16x8*>(qw + qkbase + (ti * 16 + l15) * CH + l4 * 8);
    f32x4 s[9];
    #pragma unroll
    for (int nt = 0; nt < 9; ++nt){
      f32x4 cf;
      cf[0] = __uint_as_float(cc[nt].x << 16);
      cf[1] = __uint_as_float(cc[nt].x & 0xFFFF0000u);
      cf[2] = __uint_as_float(cc[nt].y << 16);
      cf[3] = __uint_as_float(cc[nt].y & 0xFFFF0000u);
      bf16x8 bk = *reinterpret_cast<const bf16x8*>(kw + qkbase + (nt * 16 + l15) * CH + l4 * 8);
      s[nt] = __builtin_amdgcn_mfma_f32_16x16x32_bf16(aq, bk, cf, 0, 0, 0);
    }
    float invs[4];
    #pragma unroll
    for (int r = 0; r < 4; ++r){
      float sum = 0.f;
      #pragma unroll
      for (int nt = 0; nt < 9; ++nt){
        float p = exp2f(s[nt][r]);
        s[nt][r] = p; sum += p;
      }
      #pragma unroll
      for (int off = 8; off; off >>= 1) sum += __shfl_xor(sum, off, 16);
      invs[r] = 1.0f / sum;   // applied at stash
    }
    f32x4 oe = zz, oo = zz;
    #pragma unroll
    for (int kk = 0; kk < 5; ++kk){
      #pragma unroll
      for (int r = 0; r < 4; ++r){
        Pw[(l4 * 4 + r) * 40 + l15] = f2b(s[2 * kk][r]);
        if (kk < 4) Pw[(l4 * 4 + r) * 40 + 16 + l15] = f2b(s[2 * kk + 1][r]);
      }
      int j0 = kk * 32 + l4 * 8;
      int jc = (j0 < NTOK) ? j0 : 0;          // clamp tail address (stay in-bounds)
      bf16x8 ap = *reinterpret_cast<const bf16x8*>(Pw + l15 * 40 + l4 * 8);
      bf16x8 bve = *reinterpret_cast<const bf16x8*>(vw + vbase + (size_t)(2 * l15) * NTOK + jc);
      bf16x8 bvo = *reinterpret_cast<const bf16x8*>(vw + vbase + (size_t)(2 * l15 + 1) * NTOK + jc);
      if (j0 >= NTOK) ap = bf16x8{0, 0, 0, 0, 0, 0, 0, 0};   // tail K=16: zero P side
      oe = __builtin_amdgcn_mfma_f32_16x16x32_bf16(ap, bve, oe, 0, 0, 0);
      oo = __builtin_amdgcn_mfma_f32_16x16x32_bf16(ap, bvo, oo, 0, 0, 0);
    }
    #pragma unroll
    for (int r = 0; r < 4; ++r){
      size_t t = (size_t)b * NTOK + ti * 16 + l4 * 4 + r;
      float is = invs[r];
      stash32[t * 192 + 96 + h * 16 + l15] = pk2(oe[r] * is, oo[r] * is);
    }
    #pragma unroll
    for (int nt = 0; nt < 9; ++nt) cc[nt] = ccn[nt];
  }
}

// ---------------- K3: out = attn_out @ w2 + b2 — B register-stationary, one-deep A prefetch.
extern "C" __global__ __launch_bounds__(256, 2) void proj_gemm(
    const u16* __restrict__ w2t, const float* __restrict__ b2, float* __restrict__ outbuf){
  const int tid = threadIdx.x;
  const int wid = tid >> 6, lane = tid & 63, l15 = lane & 15, l4 = lane >> 4;
  const int hb = blockIdx.y;             // col half: cols hb*96 .. +96
  const f32x4 zz = {0.f, 0.f, 0.f, 0.f};

  bf16x8 bfr[6][6];
  #pragma unroll
  for (int nf = 0; nf < 6; ++nf)
    #pragma unroll
    for (int kk = 0; kk < 6; ++kk)
      bfr[nf][kk] = *reinterpret_cast<const bf16x8*>(
          w2t + (size_t)(hb * 96 + nf * 16 + l15) * CDIM + kk * 32 + l4 * 8);

  const u16* stash = reinterpret_cast<const u16*>(outbuf);
  const size_t rbase = (size_t)blockIdx.x * 256 + wid * 64;

#define LOADA(dst, mt) { \
    const u16* src_ = stash + (rbase + (mt) * 16 + l15) * 384 + 192 + l4 * 8; \
    _Pragma("unroll") \
    for (int kk = 0; kk < 6; ++kk) dst[kk] = *reinterpret_cast<const bf16x8*>(src_ + kk * 32); }

#define COMPUTE(a_, mt) { \
    f32x4 acc[6]; \
    _Pragma("unroll") \
    for (int nf = 0; nf < 6; ++nf) acc[nf] = zz; \
    _Pragma("unroll") \
    for (int kk = 0; kk < 6; ++kk) \
      _Pragma("unroll") \
      for (int nf = 0; nf < 6; ++nf) \
        acc[nf] = __builtin_amdgcn_mfma_f32_16x16x32_bf16(a_[kk], bfr[nf][kk], acc[nf], 0, 0, 0); \
    _Pragma("unroll") \
    for (int nf = 0; nf < 6; ++nf){ \
      int c = hb * 96 + nf * 16 + l15; \
      float bias = b2[c]; \
      _Pragma("unroll") \
      for (int r = 0; r < 4; ++r) \
        outbuf[(rbase + (mt) * 16 + l4 * 4 + r) * CDIM + c] = acc[nf][r] + bias; } }

  bf16x8 a0[6], a1[6];
  LOADA(a0, 0)
  LOADA(a1, 1) COMPUTE(a0, 0)
  LOADA(a0, 2) COMPUTE(a1, 1)
  LOADA(a1, 3) COMPUTE(a0, 2)
  COMPUTE(a1, 3)
#undef LOADA
#undef COMPUTE
}

extern "C" void kernel_launch(void* const* d_in, const int* in_sizes, int n_in,
                              void* d_out, int out_size, void* d_ws, size_t ws_size,
                              hipStream_t stream){
  const float* x    = (const float*)d_in[0];
  const float* w1   = (const float*)d_in[1];
  const float* b1   = (const float*)d_in[2];
  const float* w2   = (const float*)d_in[3];
  const float* b2   = (const float*)d_in[4];
  const float* bt   = (const float*)d_in[5];
  const float* mask = (const float*)d_in[6];
  const int*   pidx = (const int*)d_in[7];
  (void)in_sizes; (void)n_in; (void)out_size; (void)ws_size;

  char* ws = (char*)d_ws;
  u16*   w1tp = (u16*)(ws + OFF_W1T);
  u16*   w2t  = (u16*)(ws + OFF_W2T);
  u16*   comb = (u16*)(ws + OFF_COMB);
  u16*   qw   = (u16*)(ws + OFF_Q);
  u16*   kw   = (u16*)(ws + OFF_K);
  u16*   vw   = (u16*)(ws + OFF_V);
  float* out = (float*)d_out;

  prep_weights<<<dim3(432), dim3(256), 0, stream>>>(w1, w2, w1tp, w2t);
  prep_comb<<<dim3(384, 27), dim3(192), 0, stream>>>(bt, mask, pidx, comb);
  qkv_gemm<<<dim3(1080), dim3(256), 0, stream>>>(x, w1tp, b1, qw, kw, vw);
  attn_kernel<<<dim3(720), dim3(512), 0, stream>>>(qw, kw, vw, comb, out);
  proj_gemm<<<dim3(540, 2), dim3(256), 0, stream>>>(w2t, b2, out);
}